// Round 1
// baseline (9462.783 us; speedup 1.0000x reference)
//
#include <hip/hip_runtime.h>
#include <math.h>

#define BMT 64
#define BNT 64
#define BKT 16
#define HD 64

// C[M,N] = A[M,K] @ B[K,N] + bias[N]   (all row-major fp32)
__global__ __launch_bounds__(256) void gemm_bias(const float* __restrict__ A,
                                                 const float* __restrict__ Bm,
                                                 const float* __restrict__ bias,
                                                 float* __restrict__ C,
                                                 int M, int N, int K) {
    __shared__ float As[BKT][BMT + 1];
    __shared__ float Bs[BKT][BNT + 1];
    const int tid = threadIdx.x;
    const int tx = tid % 16;   // output col group
    const int ty = tid / 16;   // output row group
    const int block_row = blockIdx.y * BMT;
    const int block_col = blockIdx.x * BNT;

    float acc[4][4] = {};

    for (int k0 = 0; k0 < K; k0 += BKT) {
        // A tile: BMT x BKT, stored transposed As[k][m]
        for (int i = tid; i < BMT * BKT; i += 256) {
            int r = i / BKT, c = i % BKT;
            int gr = block_row + r;
            As[c][r] = (gr < M) ? A[(size_t)gr * K + (k0 + c)] : 0.f;
        }
        // B tile: BKT x BNT
        for (int i = tid; i < BKT * BNT; i += 256) {
            int r = i / BNT, c = i % BNT;
            int gc = block_col + c;
            Bs[r][c] = (gc < N) ? Bm[(size_t)(k0 + r) * N + gc] : 0.f;
        }
        __syncthreads();
        #pragma unroll
        for (int kk = 0; kk < BKT; ++kk) {
            float a[4], b[4];
            #pragma unroll
            for (int i = 0; i < 4; ++i) a[i] = As[kk][ty * 4 + i];
            #pragma unroll
            for (int j = 0; j < 4; ++j) b[j] = Bs[kk][tx * 4 + j];
            #pragma unroll
            for (int i = 0; i < 4; ++i)
                #pragma unroll
                for (int j = 0; j < 4; ++j)
                    acc[i][j] += a[i] * b[j];
        }
        __syncthreads();
    }
    #pragma unroll
    for (int i = 0; i < 4; ++i) {
        int gr = block_row + ty * 4 + i;
        if (gr >= M) continue;
        #pragma unroll
        for (int j = 0; j < 4; ++j) {
            int gc = block_col + tx * 4 + j;
            if (gc < N) C[(size_t)gr * N + gc] = acc[i][j] + bias[gc];
        }
    }
}

__device__ __forceinline__ float block_reduce_max(float v, float* red) {
    __syncthreads();  // protect red[] reuse across calls
    #pragma unroll
    for (int off = 1; off < 64; off <<= 1)
        v = fmaxf(v, __shfl_xor(v, off, 64));
    int wid = threadIdx.x >> 6;
    if ((threadIdx.x & 63) == 0) red[wid] = v;
    __syncthreads();
    if (threadIdx.x == 0) {
        float m = fmaxf(fmaxf(red[0], red[1]), fmaxf(red[2], red[3]));
        red[0] = m;
    }
    __syncthreads();
    return red[0];
}

__device__ __forceinline__ float block_reduce_sum(float v, float* red) {
    __syncthreads();
    #pragma unroll
    for (int off = 1; off < 64; off <<= 1)
        v += __shfl_xor(v, off, 64);
    int wid = threadIdx.x >> 6;
    if ((threadIdx.x & 63) == 0) red[wid] = v;
    __syncthreads();
    if (threadIdx.x == 0) red[0] = red[0] + red[1] + red[2] + red[3];
    __syncthreads();
    return red[0];
}

// One block per (b, h, i): two-pass softmax row attention.
// qkv layout: [(b*N+n)*3C + part*C + h*HD + d]
__global__ __launch_bounds__(256) void attn_kernel(const float* __restrict__ qkv,
                                                   const float* __restrict__ scale,
                                                   float* __restrict__ out,  // (B,N,C)
                                                   int Bn, int Nn, int Hn) {
    const int idx = blockIdx.x;
    const int i = idx % Nn;
    const int h = (idx / Nn) % Hn;
    const int b = idx / (Nn * Hn);
    const int tid = threadIdx.x;
    const int Cc = Hn * HD;        // 768
    const int C3 = 3 * Cc;         // 2304

    const float* qrow = qkv + (size_t)(b * Nn + i) * C3 + h * HD;
    const float* kbase = qkv + (size_t)b * Nn * C3 + Cc + h * HD;
    const float* vbase = qkv + (size_t)b * Nn * C3 + 2 * Cc + h * HD;

    __shared__ float qs[HD];
    __shared__ float sc[640];      // >= Nn scores
    __shared__ float red[4];
    __shared__ float pv[4][HD];

    if (tid < HD) qs[tid] = qrow[tid];
    __syncthreads();
    const float sl = scale[h];

    // pass 1: scores + local max
    float lmax = -INFINITY;
    for (int j = tid; j < Nn; j += 256) {
        const float* krow = kbase + (size_t)j * C3;
        float s = 0.f;
        #pragma unroll
        for (int d = 0; d < HD; d += 4) {
            float4 kv = *reinterpret_cast<const float4*>(krow + d);
            s += qs[d] * kv.x + qs[d + 1] * kv.y + qs[d + 2] * kv.z + qs[d + 3] * kv.w;
        }
        s *= sl;
        if (i >= 1 && j == i) s = -INFINITY;   // diagonal mask (rows/cols >= 1)
        sc[j] = s;
        lmax = fmaxf(lmax, s);
    }
    const float m = block_reduce_max(lmax, red);

    // pass 2: exponentiate + sum
    float lsum = 0.f;
    for (int j = tid; j < Nn; j += 256) {
        float p = expf(sc[j] - m);
        sc[j] = p;
        lsum += p;
    }
    const float total = block_reduce_sum(lsum, red);
    const float inv_sum = 1.f / total;

    // PV: thread (c = wave, d = lane) accumulates over j = c, c+4, ...
    const int d = tid & 63;
    const int c = tid >> 6;
    float acc = 0.f;
    for (int j = c; j < Nn; j += 4)
        acc += sc[j] * vbase[(size_t)j * C3 + d];
    pv[c][d] = acc;
    __syncthreads();
    if (c == 0) {
        float o = (pv[0][d] + pv[1][d] + pv[2][d] + pv[3][d]) * inv_sum;
        out[(size_t)(b * Nn + i) * Cc + h * HD + d] = o;
    }
}

extern "C" void kernel_launch(void* const* d_in, const int* in_sizes, int n_in,
                              void* d_out, int out_size, void* d_ws, size_t ws_size,
                              hipStream_t stream) {
    const float* x      = (const float*)d_in[0];
    const float* w_qkv  = (const float*)d_in[1];
    const float* b_qkv  = (const float*)d_in[2];
    const float* scale  = (const float*)d_in[3];
    const float* w_proj = (const float*)d_in[4];
    const float* b_proj = (const float*)d_in[5];
    float* out = (float*)d_out;

    const int B = 32, N = 577, C = 768, H = 12;
    const int M  = B * N;     // 18464
    const int C3 = 3 * C;     // 2304

    float* qkv      = (float*)d_ws;                  // M x 3C  (170 MB)
    float* attn_out = qkv + (size_t)M * C3;          // M x C   (57 MB)

    dim3 blk(256);
    // qkv = x @ w_qkv + b_qkv
    gemm_bias<<<dim3(C3 / BNT, (M + BMT - 1) / BMT), blk, 0, stream>>>(
        x, w_qkv, b_qkv, qkv, M, C3, C);
    // attention -> attn_out (B,N,C)
    attn_kernel<<<dim3(B * H * N), blk, 0, stream>>>(qkv, scale, attn_out, B, N, H);
    // out = attn_out @ w_proj + b_proj
    gemm_bias<<<dim3(C / BNT, (M + BMT - 1) / BMT), blk, 0, stream>>>(
        attn_out, w_proj, b_proj, out, M, C, C);
}

// Round 2
// 2155.663 us; speedup vs baseline: 4.3897x; 4.3897x over previous
//
#include <hip/hip_runtime.h>
#include <math.h>

#define BMT 64
#define BNT 64
#define BKT 16
#define HD 64
#define KVBLK 64
#define LP 72   // padded LDS row length (bf16 elems): 144B rows -> 2-way bank pattern (free)

typedef __attribute__((ext_vector_type(8))) short short8;
typedef __attribute__((ext_vector_type(4))) float f32x4;

__device__ __forceinline__ short f2bf(float f) {
    union { float f; unsigned u; } in;
    in.f = f;
    unsigned r = (in.u + 0x7fff + ((in.u >> 16) & 1)) >> 16;  // RNE
    return (short)r;
}

// ---------------- fp32 tiled GEMM (unchanged this round) ----------------
__global__ __launch_bounds__(256) void gemm_bias(const float* __restrict__ A,
                                                 const float* __restrict__ Bm,
                                                 const float* __restrict__ bias,
                                                 float* __restrict__ C,
                                                 int M, int N, int K) {
    __shared__ float As[BKT][BMT + 1];
    __shared__ float Bs[BKT][BNT + 1];
    const int tid = threadIdx.x;
    const int tx = tid % 16;
    const int ty = tid / 16;
    const int block_row = blockIdx.y * BMT;
    const int block_col = blockIdx.x * BNT;

    float acc[4][4] = {};

    for (int k0 = 0; k0 < K; k0 += BKT) {
        for (int i = tid; i < BMT * BKT; i += 256) {
            int r = i / BKT, c = i % BKT;
            int gr = block_row + r;
            As[c][r] = (gr < M) ? A[(size_t)gr * K + (k0 + c)] : 0.f;
        }
        for (int i = tid; i < BKT * BNT; i += 256) {
            int r = i / BNT, c = i % BNT;
            int gc = block_col + c;
            Bs[r][c] = (gc < N) ? Bm[(size_t)(k0 + r) * N + gc] : 0.f;
        }
        __syncthreads();
        #pragma unroll
        for (int kk = 0; kk < BKT; ++kk) {
            float a[4], b[4];
            #pragma unroll
            for (int i = 0; i < 4; ++i) a[i] = As[kk][ty * 4 + i];
            #pragma unroll
            for (int j = 0; j < 4; ++j) b[j] = Bs[kk][tx * 4 + j];
            #pragma unroll
            for (int i = 0; i < 4; ++i)
                #pragma unroll
                for (int j = 0; j < 4; ++j)
                    acc[i][j] += a[i] * b[j];
        }
        __syncthreads();
    }
    #pragma unroll
    for (int i = 0; i < 4; ++i) {
        int gr = block_row + ty * 4 + i;
        if (gr >= M) continue;
        #pragma unroll
        for (int j = 0; j < 4; ++j) {
            int gc = block_col + tx * 4 + j;
            if (gc < N) C[(size_t)gr * N + gc] = acc[i][j] + bias[gc];
        }
    }
}

// ---------------- flash attention, bf16 MFMA ----------------
// Block = (b, h, 64 q-rows). 4 waves x 16 q-rows. KV tiles of 64 staged in LDS.
// mfma_f32_16x16x32_bf16 layouts (verified m89/m91):
//   A[i][k]: i = lane%16, k = (lane/16)*8 + e   (8 consecutive k per lane)
//   B[k][j]: j = lane%16, k = (lane/16)*8 + e
//   D[i][j]: j = lane%16, i = (lane/16)*4 + reg
__global__ __launch_bounds__(256) void flash_attn(const float* __restrict__ qkv,
                                                  const float* __restrict__ scale,
                                                  float* __restrict__ out) {
    constexpr int Nn = 577, Cc = 768, C3 = 2304;
    const int q0 = blockIdx.x * 64;
    const int h  = blockIdx.y;
    const int b  = blockIdx.z;
    const int tid  = threadIdx.x;
    const int w    = tid >> 6;
    const int lane = tid & 63;
    const int g    = lane >> 4;
    const int l16  = lane & 15;

    __shared__ alignas(16) short Ks[KVBLK][LP];   // K[key][dim]
    __shared__ alignas(16) short Vts[HD][LP];     // V^T[dim][key]
    __shared__ alignas(16) short Ps[4][16][LP];   // per-wave P[i][j]

    const float sl = scale[h];
    const float* base = qkv + (size_t)b * Nn * C3;

    // --- Q fragments (A operand), held in registers for the whole kernel ---
    const int qrow = q0 + w * 16 + l16;
    const int qr = qrow < Nn ? qrow : Nn - 1;     // clamp; garbage rows never stored
    const float* qp = base + (size_t)qr * C3 + h * HD;
    short8 aq[2];
    #pragma unroll
    for (int c = 0; c < 2; ++c) {
        float4 u = *reinterpret_cast<const float4*>(qp + 32 * c + 8 * g);
        float4 v = *reinterpret_cast<const float4*>(qp + 32 * c + 8 * g + 4);
        short8 a;
        a[0] = f2bf(u.x); a[1] = f2bf(u.y); a[2] = f2bf(u.z); a[3] = f2bf(u.w);
        a[4] = f2bf(v.x); a[5] = f2bf(v.y); a[6] = f2bf(v.z); a[7] = f2bf(v.w);
        aq[c] = a;
    }

    f32x4 oacc[4] = {};            // O[i][n]: n = l16 + 16*df, i = g*4 + r
    float mrun[4], lrun[4];
    #pragma unroll
    for (int r = 0; r < 4; ++r) { mrun[r] = -INFINITY; lrun[r] = 0.f; }

    const int tr = tid >> 2;           // staging: row 0..63
    const int tc = (tid & 3) * 16;     // staging: dim col start
    const float* kglob = base + Cc + h * HD;
    const float* vglob = base + 2 * Cc + h * HD;

    for (int kv0 = 0; kv0 < Nn; kv0 += KVBLK) {
        // ---- stage K tile and transposed V tile (fp32 -> bf16) ----
        {
            const int kr = kv0 + tr;
            short tk[16], tv[16];
            if (kr < Nn) {
                const float* ksrc = kglob + (size_t)kr * C3 + tc;
                const float* vsrc = vglob + (size_t)kr * C3 + tc;
                #pragma unroll
                for (int i = 0; i < 16; i += 4) {
                    float4 k4 = *reinterpret_cast<const float4*>(ksrc + i);
                    tk[i] = f2bf(k4.x); tk[i+1] = f2bf(k4.y);
                    tk[i+2] = f2bf(k4.z); tk[i+3] = f2bf(k4.w);
                    float4 v4 = *reinterpret_cast<const float4*>(vsrc + i);
                    tv[i] = f2bf(v4.x); tv[i+1] = f2bf(v4.y);
                    tv[i+2] = f2bf(v4.z); tv[i+3] = f2bf(v4.w);
                }
            } else {
                #pragma unroll
                for (int i = 0; i < 16; ++i) { tk[i] = 0; tv[i] = 0; }
            }
            short8 k0v, k1v;
            #pragma unroll
            for (int i = 0; i < 8; ++i) { k0v[i] = tk[i]; k1v[i] = tk[i + 8]; }
            *reinterpret_cast<short8*>(&Ks[tr][tc])     = k0v;
            *reinterpret_cast<short8*>(&Ks[tr][tc + 8]) = k1v;
            #pragma unroll
            for (int i = 0; i < 16; ++i) Vts[tc + i][tr] = tv[i];
        }
        __syncthreads();

        // ---- S = Q @ K^T  (16 x 64 per wave) ----
        f32x4 sacc[4] = {};
        #pragma unroll
        for (int f = 0; f < 4; ++f) {
            #pragma unroll
            for (int c = 0; c < 2; ++c) {
                short8 bk = *reinterpret_cast<const short8*>(&Ks[16 * f + l16][32 * c + 8 * g]);
                sacc[f] = __builtin_amdgcn_mfma_f32_16x16x32_bf16(aq[c], bk, sacc[f], 0, 0, 0);
            }
        }

        // ---- masking + online softmax (rows live in C-layout) ----
        float pr[4][4];   // [f][r]
        #pragma unroll
        for (int f = 0; f < 4; ++f) {
            const int jg = kv0 + 16 * f + l16;
            #pragma unroll
            for (int r = 0; r < 4; ++r) {
                float s = sacc[f][r] * sl;
                const int ig = q0 + w * 16 + g * 4 + r;
                if (jg >= Nn || (jg == ig && ig >= 1)) s = -INFINITY;
                pr[f][r] = s;
            }
        }
        #pragma unroll
        for (int r = 0; r < 4; ++r) {
            float mx = fmaxf(fmaxf(pr[0][r], pr[1][r]), fmaxf(pr[2][r], pr[3][r]));
            mx = fmaxf(mx, __shfl_xor(mx, 1, 64));
            mx = fmaxf(mx, __shfl_xor(mx, 2, 64));
            mx = fmaxf(mx, __shfl_xor(mx, 4, 64));
            mx = fmaxf(mx, __shfl_xor(mx, 8, 64));
            const float mnew = fmaxf(mrun[r], mx);
            const float fac = __expf(mrun[r] - mnew);
            mrun[r] = mnew;
            float sum = 0.f;
            #pragma unroll
            for (int f = 0; f < 4; ++f) {
                float p = __expf(pr[f][r] - mnew);
                pr[f][r] = p;
                sum += p;
            }
            sum += __shfl_xor(sum, 1, 64);
            sum += __shfl_xor(sum, 2, 64);
            sum += __shfl_xor(sum, 4, 64);
            sum += __shfl_xor(sum, 8, 64);
            lrun[r] = lrun[r] * fac + sum;
            #pragma unroll
            for (int df = 0; df < 4; ++df) oacc[df][r] *= fac;
        }

        // ---- P relayout through per-wave LDS (C-layout -> A-layout) ----
        #pragma unroll
        for (int f = 0; f < 4; ++f)
            #pragma unroll
            for (int r = 0; r < 4; ++r)
                Ps[w][g * 4 + r][16 * f + l16] = f2bf(pr[f][r]);
        asm volatile("s_waitcnt lgkmcnt(0)" ::: "memory");

        // ---- O += P @ V ----
        #pragma unroll
        for (int c = 0; c < 2; ++c) {
            short8 pa = *reinterpret_cast<const short8*>(&Ps[w][l16][32 * c + 8 * g]);
            #pragma unroll
            for (int df = 0; df < 4; ++df) {
                short8 bv = *reinterpret_cast<const short8*>(&Vts[16 * df + l16][32 * c + 8 * g]);
                oacc[df] = __builtin_amdgcn_mfma_f32_16x16x32_bf16(pa, bv, oacc[df], 0, 0, 0);
            }
        }
        __syncthreads();
    }

    // ---- epilogue: normalize + store ----
    float inv[4];
    #pragma unroll
    for (int r = 0; r < 4; ++r) inv[r] = 1.f / lrun[r];
    #pragma unroll
    for (int df = 0; df < 4; ++df) {
        #pragma unroll
        for (int r = 0; r < 4; ++r) {
            const int ig = q0 + w * 16 + g * 4 + r;
            if (ig < Nn)
                out[(size_t)(b * Nn + ig) * Cc + h * HD + 16 * df + l16] = oacc[df][r] * inv[r];
        }
    }
}

extern "C" void kernel_launch(void* const* d_in, const int* in_sizes, int n_in,
                              void* d_out, int out_size, void* d_ws, size_t ws_size,
                              hipStream_t stream) {
    const float* x      = (const float*)d_in[0];
    const float* w_qkv  = (const float*)d_in[1];
    const float* b_qkv  = (const float*)d_in[2];
    const float* scale  = (const float*)d_in[3];
    const float* w_proj = (const float*)d_in[4];
    const float* b_proj = (const float*)d_in[5];
    float* out = (float*)d_out;

    const int B = 32, N = 577, C = 768, H = 12;
    const int M  = B * N;     // 18464
    const int C3 = 3 * C;     // 2304

    float* qkv      = (float*)d_ws;                  // M x 3C
    float* attn_out = qkv + (size_t)M * C3;          // M x C

    dim3 blk(256);
    gemm_bias<<<dim3(C3 / BNT, (M + BMT - 1) / BMT), blk, 0, stream>>>(
        x, w_qkv, b_qkv, qkv, M, C3, C);

    flash_attn<<<dim3((N + 63) / 64, H, B), blk, 0, stream>>>(qkv, scale, attn_out);

    gemm_bias<<<dim3(C / BNT, (M + BMT - 1) / BMT), blk, 0, stream>>>(
        attn_out, w_proj, b_proj, out, M, C, C);
}

// Round 3
// 379.882 us; speedup vs baseline: 24.9098x; 5.6746x over previous
//
#include <hip/hip_runtime.h>
#include <math.h>

#define HD 64
#define KVBLK 64
#define LP 72   // padded LDS row (bf16 elems) for attention tiles

typedef __attribute__((ext_vector_type(8))) short short8;
typedef __attribute__((ext_vector_type(4))) short short4v;
typedef __attribute__((ext_vector_type(4))) float f32x4;

__device__ __forceinline__ short f2bf(float f) {
    union { float f; unsigned u; } in;
    in.f = f;
    unsigned r = (in.u + 0x7fff + ((in.u >> 16) & 1)) >> 16;  // RNE
    return (short)r;
}

// ---------------- fp32 -> bf16 convert (4 elems/thread) ----------------
__global__ __launch_bounds__(256) void convert_bf16(const float* __restrict__ in,
                                                    short* __restrict__ out, long n4) {
    long i = blockIdx.x * 256L + threadIdx.x;
    if (i >= n4) return;
    float4 v = reinterpret_cast<const float4*>(in)[i];
    short4v o;
    o[0] = f2bf(v.x); o[1] = f2bf(v.y); o[2] = f2bf(v.z); o[3] = f2bf(v.w);
    reinterpret_cast<short4v*>(out)[i] = o;
}

// ------------- transpose + convert: in [K][N] fp32 -> out [N][K] bf16 -------------
__global__ __launch_bounds__(256) void transpose_bf16(const float* __restrict__ in,
                                                      short* __restrict__ out, int K, int N) {
    __shared__ float tile[32][33];
    const int n0 = blockIdx.x * 32, k0 = blockIdx.y * 32;
    const int tx = threadIdx.x & 31, ty = threadIdx.x >> 5;
    #pragma unroll
    for (int i = ty; i < 32; i += 8)
        tile[i][tx] = in[(size_t)(k0 + i) * N + n0 + tx];
    __syncthreads();
    #pragma unroll
    for (int i = ty; i < 32; i += 8)
        out[(size_t)(n0 + i) * K + k0 + tx] = f2bf(tile[tx][i]);
}

// ---------------- bf16 MFMA GEMM (m97 structure) ----------------
// C[M][N] fp32 = A[M][K] bf16 @ Bt[N][K]^T bf16 + bias.
// 128x128 tile, BK=64, 4 waves (2x2 of 64x64), global_load_lds width 16.
__global__ __launch_bounds__(256) void gemm_bf16(const short* __restrict__ A,
                                                 const short* __restrict__ Bt,
                                                 const float* __restrict__ bias,
                                                 float* __restrict__ C,
                                                 int M, int N, int K) {
    __shared__ short As[128 * 64];
    __shared__ short Bs[128 * 64];
    const int tid = threadIdx.x;
    const int w = tid >> 6, lane = tid & 63;
    const int g = lane >> 4, l16 = lane & 15;
    const int m0 = blockIdx.y * 128, n0 = blockIdx.x * 128;
    const int wm = (w >> 1) * 64, wn = (w & 1) * 64;

    f32x4 acc[4][4] = {};

    const int lr = lane >> 3;        // row 0..7 within the 8-row chunk one inst stages
    const int lc = (lane & 7) * 8;   // col (elems) within the 64-wide K slab

    for (int k0 = 0; k0 < K; k0 += 64) {
        #pragma unroll
        for (int t = 0; t < 4; ++t) {
            const int r = 32 * w + 8 * t + lr;
            long arow = m0 + r; if (arow > M - 1) arow = M - 1;   // clamp tail rows
            const short* ga = A + arow * K + k0 + lc;
            const short* gb = Bt + (size_t)(n0 + r) * K + k0 + lc;
            __builtin_amdgcn_global_load_lds(
                (const __attribute__((address_space(1))) unsigned*)ga,
                (__attribute__((address_space(3))) unsigned*)&As[(32 * w + 8 * t) * 64],
                16, 0, 0);
            __builtin_amdgcn_global_load_lds(
                (const __attribute__((address_space(1))) unsigned*)gb,
                (__attribute__((address_space(3))) unsigned*)&Bs[(32 * w + 8 * t) * 64],
                16, 0, 0);
        }
        __syncthreads();
        #pragma unroll
        for (int ks = 0; ks < 2; ++ks) {
            short8 af[4], bfr[4];
            #pragma unroll
            for (int mi = 0; mi < 4; ++mi)
                af[mi] = *reinterpret_cast<const short8*>(
                    &As[(wm + mi * 16 + l16) * 64 + ks * 32 + g * 8]);
            #pragma unroll
            for (int ni = 0; ni < 4; ++ni)
                bfr[ni] = *reinterpret_cast<const short8*>(
                    &Bs[(wn + ni * 16 + l16) * 64 + ks * 32 + g * 8]);
            #pragma unroll
            for (int mi = 0; mi < 4; ++mi)
                #pragma unroll
                for (int ni = 0; ni < 4; ++ni)
                    acc[mi][ni] = __builtin_amdgcn_mfma_f32_16x16x32_bf16(
                        af[mi], bfr[ni], acc[mi][ni], 0, 0, 0);
        }
        __syncthreads();
    }

    float bv[4];
    #pragma unroll
    for (int ni = 0; ni < 4; ++ni) bv[ni] = bias[n0 + wn + ni * 16 + l16];
    #pragma unroll
    for (int mi = 0; mi < 4; ++mi) {
        #pragma unroll
        for (int r = 0; r < 4; ++r) {
            const int row = m0 + wm + mi * 16 + g * 4 + r;
            if (row < M) {
                #pragma unroll
                for (int ni = 0; ni < 4; ++ni)
                    C[(size_t)row * N + n0 + wn + ni * 16 + l16] = acc[mi][ni][r] + bv[ni];
            }
        }
    }
}

// ---------------- flash attention, bf16 MFMA (out now bf16) ----------------
__global__ __launch_bounds__(256) void flash_attn(const float* __restrict__ qkv,
                                                  const float* __restrict__ scale,
                                                  short* __restrict__ out) {
    constexpr int Nn = 577, Cc = 768, C3 = 2304;
    const int q0 = blockIdx.x * 64;
    const int h  = blockIdx.y;
    const int b  = blockIdx.z;
    const int tid  = threadIdx.x;
    const int w    = tid >> 6;
    const int lane = tid & 63;
    const int g    = lane >> 4;
    const int l16  = lane & 15;

    __shared__ alignas(16) short Ks[KVBLK][LP];
    __shared__ alignas(16) short Vts[HD][LP];
    __shared__ alignas(16) short Ps[4][16][LP];

    const float sl = scale[h];
    const float* base = qkv + (size_t)b * Nn * C3;

    const int qrow = q0 + w * 16 + l16;
    const int qr = qrow < Nn ? qrow : Nn - 1;
    const float* qp = base + (size_t)qr * C3 + h * HD;
    short8 aq[2];
    #pragma unroll
    for (int c = 0; c < 2; ++c) {
        float4 u = *reinterpret_cast<const float4*>(qp + 32 * c + 8 * g);
        float4 v = *reinterpret_cast<const float4*>(qp + 32 * c + 8 * g + 4);
        short8 a;
        a[0] = f2bf(u.x); a[1] = f2bf(u.y); a[2] = f2bf(u.z); a[3] = f2bf(u.w);
        a[4] = f2bf(v.x); a[5] = f2bf(v.y); a[6] = f2bf(v.z); a[7] = f2bf(v.w);
        aq[c] = a;
    }

    f32x4 oacc[4] = {};
    float mrun[4], lrun[4];
    #pragma unroll
    for (int r = 0; r < 4; ++r) { mrun[r] = -INFINITY; lrun[r] = 0.f; }

    const int tr = tid >> 2;
    const int tc = (tid & 3) * 16;
    const float* kglob = base + Cc + h * HD;
    const float* vglob = base + 2 * Cc + h * HD;

    for (int kv0 = 0; kv0 < Nn; kv0 += KVBLK) {
        {
            const int kr = kv0 + tr;
            short tk[16], tv[16];
            if (kr < Nn) {
                const float* ksrc = kglob + (size_t)kr * C3 + tc;
                const float* vsrc = vglob + (size_t)kr * C3 + tc;
                #pragma unroll
                for (int i = 0; i < 16; i += 4) {
                    float4 k4 = *reinterpret_cast<const float4*>(ksrc + i);
                    tk[i] = f2bf(k4.x); tk[i+1] = f2bf(k4.y);
                    tk[i+2] = f2bf(k4.z); tk[i+3] = f2bf(k4.w);
                    float4 v4 = *reinterpret_cast<const float4*>(vsrc + i);
                    tv[i] = f2bf(v4.x); tv[i+1] = f2bf(v4.y);
                    tv[i+2] = f2bf(v4.z); tv[i+3] = f2bf(v4.w);
                }
            } else {
                #pragma unroll
                for (int i = 0; i < 16; ++i) { tk[i] = 0; tv[i] = 0; }
            }
            short8 k0v, k1v;
            #pragma unroll
            for (int i = 0; i < 8; ++i) { k0v[i] = tk[i]; k1v[i] = tk[i + 8]; }
            *reinterpret_cast<short8*>(&Ks[tr][tc])     = k0v;
            *reinterpret_cast<short8*>(&Ks[tr][tc + 8]) = k1v;
            #pragma unroll
            for (int i = 0; i < 16; ++i) Vts[tc + i][tr] = tv[i];
        }
        __syncthreads();

        f32x4 sacc[4] = {};
        #pragma unroll
        for (int f = 0; f < 4; ++f) {
            #pragma unroll
            for (int c = 0; c < 2; ++c) {
                short8 bk = *reinterpret_cast<const short8*>(&Ks[16 * f + l16][32 * c + 8 * g]);
                sacc[f] = __builtin_amdgcn_mfma_f32_16x16x32_bf16(aq[c], bk, sacc[f], 0, 0, 0);
            }
        }

        float pr[4][4];
        #pragma unroll
        for (int f = 0; f < 4; ++f) {
            const int jg = kv0 + 16 * f + l16;
            #pragma unroll
            for (int r = 0; r < 4; ++r) {
                float s = sacc[f][r] * sl;
                const int ig = q0 + w * 16 + g * 4 + r;
                if (jg >= Nn || (jg == ig && ig >= 1)) s = -INFINITY;
                pr[f][r] = s;
            }
        }
        #pragma unroll
        for (int r = 0; r < 4; ++r) {
            float mx = fmaxf(fmaxf(pr[0][r], pr[1][r]), fmaxf(pr[2][r], pr[3][r]));
            mx = fmaxf(mx, __shfl_xor(mx, 1, 64));
            mx = fmaxf(mx, __shfl_xor(mx, 2, 64));
            mx = fmaxf(mx, __shfl_xor(mx, 4, 64));
            mx = fmaxf(mx, __shfl_xor(mx, 8, 64));
            const float mnew = fmaxf(mrun[r], mx);
            const float fac = __expf(mrun[r] - mnew);
            mrun[r] = mnew;
            float sum = 0.f;
            #pragma unroll
            for (int f = 0; f < 4; ++f) {
                float p = __expf(pr[f][r] - mnew);
                pr[f][r] = p;
                sum += p;
            }
            sum += __shfl_xor(sum, 1, 64);
            sum += __shfl_xor(sum, 2, 64);
            sum += __shfl_xor(sum, 4, 64);
            sum += __shfl_xor(sum, 8, 64);
            lrun[r] = lrun[r] * fac + sum;
            #pragma unroll
            for (int df = 0; df < 4; ++df) oacc[df][r] *= fac;
        }

        #pragma unroll
        for (int f = 0; f < 4; ++f)
            #pragma unroll
            for (int r = 0; r < 4; ++r)
                Ps[w][g * 4 + r][16 * f + l16] = f2bf(pr[f][r]);
        asm volatile("s_waitcnt lgkmcnt(0)" ::: "memory");

        #pragma unroll
        for (int c = 0; c < 2; ++c) {
            short8 pa = *reinterpret_cast<const short8*>(&Ps[w][l16][32 * c + 8 * g]);
            #pragma unroll
            for (int df = 0; df < 4; ++df) {
                short8 bv = *reinterpret_cast<const short8*>(&Vts[16 * df + l16][32 * c + 8 * g]);
                oacc[df] = __builtin_amdgcn_mfma_f32_16x16x32_bf16(pa, bv, oacc[df], 0, 0, 0);
            }
        }
        __syncthreads();
    }

    float inv[4];
    #pragma unroll
    for (int r = 0; r < 4; ++r) inv[r] = 1.f / lrun[r];
    #pragma unroll
    for (int df = 0; df < 4; ++df) {
        #pragma unroll
        for (int r = 0; r < 4; ++r) {
            const int ig = q0 + w * 16 + g * 4 + r;
            if (ig < Nn)
                out[(size_t)(b * Nn + ig) * Cc + h * HD + 16 * df + l16] =
                    f2bf(oacc[df][r] * inv[r]);
        }
    }
}

extern "C" void kernel_launch(void* const* d_in, const int* in_sizes, int n_in,
                              void* d_out, int out_size, void* d_ws, size_t ws_size,
                              hipStream_t stream) {
    const float* x      = (const float*)d_in[0];
    const float* w_qkv  = (const float*)d_in[1];
    const float* b_qkv  = (const float*)d_in[2];
    const float* scale  = (const float*)d_in[3];
    const float* w_proj = (const float*)d_in[4];
    const float* b_proj = (const float*)d_in[5];
    float* out = (float*)d_out;

    const int B = 32, N = 577, C = 768, H = 12;
    const int M  = B * N;     // 18464
    const int C3 = 3 * C;     // 2304

    // workspace layout (~221 MB)
    float* qkv     = (float*)d_ws;                       // M x 3C fp32
    short* attn_o  = (short*)(qkv + (size_t)M * C3);     // M x C bf16
    short* xb      = attn_o + (size_t)M * C;             // M x C bf16
    short* wqkvT   = xb + (size_t)M * C;                 // 3C x C bf16
    short* wprojT  = wqkvT + (size_t)C3 * C;             // C x C bf16

    dim3 blk(256);
    const long n4 = (long)M * C / 4;
    convert_bf16<<<dim3((n4 + 255) / 256), blk, 0, stream>>>(x, xb, n4);
    transpose_bf16<<<dim3(C3 / 32, C / 32), blk, 0, stream>>>(w_qkv, wqkvT, C, C3);
    transpose_bf16<<<dim3(C / 32, C / 32), blk, 0, stream>>>(w_proj, wprojT, C, C);

    gemm_bf16<<<dim3(C3 / 128, (M + 127) / 128), blk, 0, stream>>>(
        xb, wqkvT, b_qkv, qkv, M, C3, C);

    flash_attn<<<dim3((N + 63) / 64, H, B), blk, 0, stream>>>(qkv, scale, attn_o);

    gemm_bf16<<<dim3(C / 128, (M + 127) / 128), blk, 0, stream>>>(
        attn_o, wprojT, b_proj, out, M, C, C);
}

// Round 4
// 349.142 us; speedup vs baseline: 27.1030x; 1.0880x over previous
//
#include <hip/hip_runtime.h>
#include <math.h>

#define HD 64
#define KVBLK 64
#define LP 72   // padded LDS row (bf16 elems) for V^T / P tiles

typedef __attribute__((ext_vector_type(8))) short short8;
typedef __attribute__((ext_vector_type(4))) short short4v;
typedef __attribute__((ext_vector_type(4))) float f32x4;

__device__ __forceinline__ short f2bf(float f) {
    union { float f; unsigned u; } in;
    in.f = f;
    unsigned r = (in.u + 0x7fff + ((in.u >> 16) & 1)) >> 16;  // RNE
    return (short)r;
}

// ---------------- fp32 -> bf16 convert (4 elems/thread) ----------------
__global__ __launch_bounds__(256) void convert_bf16(const float* __restrict__ in,
                                                    short* __restrict__ out, long n4) {
    long i = blockIdx.x * 256L + threadIdx.x;
    if (i >= n4) return;
    float4 v = reinterpret_cast<const float4*>(in)[i];
    short4v o;
    o[0] = f2bf(v.x); o[1] = f2bf(v.y); o[2] = f2bf(v.z); o[3] = f2bf(v.w);
    reinterpret_cast<short4v*>(out)[i] = o;
}

// ------------- transpose + convert: in [K][N] fp32 -> out [N][K] bf16 -------------
__global__ __launch_bounds__(256) void transpose_bf16(const float* __restrict__ in,
                                                      short* __restrict__ out, int K, int N) {
    __shared__ float tile[32][33];
    const int n0 = blockIdx.x * 32, k0 = blockIdx.y * 32;
    const int tx = threadIdx.x & 31, ty = threadIdx.x >> 5;
    #pragma unroll
    for (int i = ty; i < 32; i += 8)
        tile[i][tx] = in[(size_t)(k0 + i) * N + n0 + tx];
    __syncthreads();
    #pragma unroll
    for (int i = ty; i < 32; i += 8)
        out[(size_t)(n0 + i) * K + k0 + tx] = f2bf(tile[tx][i]);
}

// ---------------- bf16 MFMA GEMM (m97 structure), templated output ----------------
// C[M][N] OutT = A[M][K] bf16 @ Bt[N][K]^T bf16 + bias(fp32).
template <typename OutT>
__global__ __launch_bounds__(256) void gemm_bf16(const short* __restrict__ A,
                                                 const short* __restrict__ Bt,
                                                 const float* __restrict__ bias,
                                                 OutT* __restrict__ C,
                                                 int M, int N, int K) {
    __shared__ short As[128 * 64];
    __shared__ short Bs[128 * 64];
    const int tid = threadIdx.x;
    const int w = tid >> 6, lane = tid & 63;
    const int g = lane >> 4, l16 = lane & 15;
    const int m0 = blockIdx.y * 128, n0 = blockIdx.x * 128;
    const int wm = (w >> 1) * 64, wn = (w & 1) * 64;

    f32x4 acc[4][4] = {};

    const int lr = lane >> 3;        // row within 8-row chunk
    const int lc = (lane & 7) * 8;   // col within the 64-wide K slab

    for (int k0 = 0; k0 < K; k0 += 64) {
        #pragma unroll
        for (int t = 0; t < 4; ++t) {
            const int r = 32 * w + 8 * t + lr;
            long arow = m0 + r; if (arow > M - 1) arow = M - 1;
            const short* ga = A + arow * K + k0 + lc;
            const short* gb = Bt + (size_t)(n0 + r) * K + k0 + lc;
            __builtin_amdgcn_global_load_lds(
                (const __attribute__((address_space(1))) unsigned*)ga,
                (__attribute__((address_space(3))) unsigned*)&As[(32 * w + 8 * t) * 64],
                16, 0, 0);
            __builtin_amdgcn_global_load_lds(
                (const __attribute__((address_space(1))) unsigned*)gb,
                (__attribute__((address_space(3))) unsigned*)&Bs[(32 * w + 8 * t) * 64],
                16, 0, 0);
        }
        __syncthreads();
        #pragma unroll
        for (int ks = 0; ks < 2; ++ks) {
            short8 af[4], bfr[4];
            #pragma unroll
            for (int mi = 0; mi < 4; ++mi)
                af[mi] = *reinterpret_cast<const short8*>(
                    &As[(wm + mi * 16 + l16) * 64 + ks * 32 + g * 8]);
            #pragma unroll
            for (int ni = 0; ni < 4; ++ni)
                bfr[ni] = *reinterpret_cast<const short8*>(
                    &Bs[(wn + ni * 16 + l16) * 64 + ks * 32 + g * 8]);
            #pragma unroll
            for (int mi = 0; mi < 4; ++mi)
                #pragma unroll
                for (int ni = 0; ni < 4; ++ni)
                    acc[mi][ni] = __builtin_amdgcn_mfma_f32_16x16x32_bf16(
                        af[mi], bfr[ni], acc[mi][ni], 0, 0, 0);
        }
        __syncthreads();
    }

    float bv[4];
    #pragma unroll
    for (int ni = 0; ni < 4; ++ni) bv[ni] = bias[n0 + wn + ni * 16 + l16];
    #pragma unroll
    for (int mi = 0; mi < 4; ++mi) {
        #pragma unroll
        for (int r = 0; r < 4; ++r) {
            const int row = m0 + wm + mi * 16 + g * 4 + r;
            if (row < M) {
                #pragma unroll
                for (int ni = 0; ni < 4; ++ni) {
                    float val = acc[mi][ni][r] + bv[ni];
                    if constexpr (__is_same(OutT, float))
                        C[(size_t)row * N + n0 + wn + ni * 16 + l16] = val;
                    else
                        C[(size_t)row * N + n0 + wn + ni * 16 + l16] = f2bf(val);
                }
            }
        }
    }
}

// ---------------- flash attention, bf16 in / bf16 out ----------------
// Block = (b, h, 64 q rows), 4 waves x 16 rows. XCD-swizzled 1D grid.
// K tile: global_load_lds into linear LDS with XOR-swizzled source; read with same XOR.
__global__ __launch_bounds__(256) void flash_attn(const short* __restrict__ qkvb,
                                                  const float* __restrict__ scale,
                                                  short* __restrict__ out) {
    constexpr int Nn = 577, Cc = 768, C3 = 2304, NQB = 10, NH = 12;
    // T1: 3840 blocks, 8 XCDs, 480 per XCD; group all 10 q-blocks of a (b,h) per XCD
    const int bid = blockIdx.x;
    const int swz = (bid & 7) * 480 + (bid >> 3);
    const int q0 = (swz % NQB) * 64;
    const int h  = (swz / NQB) % NH;
    const int b  = swz / (NQB * NH);

    const int tid  = threadIdx.x;
    const int w    = tid >> 6;
    const int lane = tid & 63;
    const int g    = lane >> 4;
    const int l16  = lane & 15;

    __shared__ alignas(16) short Ks[KVBLK * HD];   // linear, XOR-swizzled content
    __shared__ alignas(16) short Vts[HD][LP];      // V^T[dim][key], padded
    __shared__ alignas(16) short Ps[4][16][LP];    // per-wave P

    const float sl = scale[h];
    const short* base = qkvb + (size_t)b * Nn * C3;
    const short* kglob = base + Cc + h * HD;
    const short* vglob = base + 2 * Cc + h * HD;

    // Q fragments: direct bf16 loads
    const int qrow = q0 + w * 16 + l16;
    const int qr = qrow < Nn ? qrow : Nn - 1;
    const short* qp = base + (size_t)qr * C3 + h * HD;
    short8 aq[2];
    aq[0] = *reinterpret_cast<const short8*>(qp + 8 * g);
    aq[1] = *reinterpret_cast<const short8*>(qp + 32 + 8 * g);

    f32x4 oacc[4] = {};
    float mrun[4], lrun[4];
    #pragma unroll
    for (int r = 0; r < 4; ++r) { mrun[r] = -INFINITY; lrun[r] = 0.f; }

    // V staging coords (reg-staged transpose)
    const int tr = tid >> 2;            // key row 0..63
    const int tc = (tid & 3) * 16;      // dim col start
    // K staging coords (global_load_lds): lane covers key 8i+(lane>>3), slot lane&7
    const int kst_row = lane >> 3;                       // 0..7 within chunk
    const int kst_dblk = (lane & 7) ^ (lane >> 3);       // pre-swizzled source dim block

    for (int kv0 = 0; kv0 < Nn; kv0 += KVBLK) {
        // ---- K tile via global_load_lds (2 insts per wave, 8 total) ----
        #pragma unroll
        for (int t = 0; t < 2; ++t) {
            const int i = 2 * w + t;
            int kr = kv0 + 8 * i + kst_row;
            if (kr > Nn - 1) kr = Nn - 1;
            const short* src = kglob + (size_t)kr * C3 + kst_dblk * 8;
            __builtin_amdgcn_global_load_lds(
                (const __attribute__((address_space(1))) unsigned*)src,
                (__attribute__((address_space(3))) unsigned*)&Ks[i * 512],
                16, 0, 0);
        }
        // ---- V tile: bf16 short8 loads, transposed scalar LDS stores ----
        {
            int kr = kv0 + tr; if (kr > Nn - 1) kr = Nn - 1;
            const short* vsrc = vglob + (size_t)kr * C3 + tc;
            short8 v0 = *reinterpret_cast<const short8*>(vsrc);
            short8 v1 = *reinterpret_cast<const short8*>(vsrc + 8);
            #pragma unroll
            for (int i = 0; i < 8; ++i) {
                Vts[tc + i][tr]     = v0[i];
                Vts[tc + 8 + i][tr] = v1[i];
            }
        }
        __syncthreads();

        // ---- S = Q @ K^T ----
        f32x4 sacc[4] = {};
        #pragma unroll
        for (int f = 0; f < 4; ++f) {
            #pragma unroll
            for (int c = 0; c < 2; ++c) {
                const int slot = (4 * c + g) ^ (l16 & 7);
                short8 bk = *reinterpret_cast<const short8*>(
                    &Ks[(16 * f + l16) * 64 + slot * 8]);
                sacc[f] = __builtin_amdgcn_mfma_f32_16x16x32_bf16(aq[c], bk, sacc[f], 0, 0, 0);
            }
        }

        // ---- masking + online softmax ----
        float pr[4][4];
        #pragma unroll
        for (int f = 0; f < 4; ++f) {
            const int jg = kv0 + 16 * f + l16;
            #pragma unroll
            for (int r = 0; r < 4; ++r) {
                float s = sacc[f][r] * sl;
                const int ig = q0 + w * 16 + g * 4 + r;
                if (jg >= Nn || (jg == ig && ig >= 1)) s = -INFINITY;
                pr[f][r] = s;
            }
        }
        #pragma unroll
        for (int r = 0; r < 4; ++r) {
            float mx = fmaxf(fmaxf(pr[0][r], pr[1][r]), fmaxf(pr[2][r], pr[3][r]));
            mx = fmaxf(mx, __shfl_xor(mx, 1, 64));
            mx = fmaxf(mx, __shfl_xor(mx, 2, 64));
            mx = fmaxf(mx, __shfl_xor(mx, 4, 64));
            mx = fmaxf(mx, __shfl_xor(mx, 8, 64));
            const float mnew = fmaxf(mrun[r], mx);
            const float fac = __expf(mrun[r] - mnew);
            mrun[r] = mnew;
            float sum = 0.f;
            #pragma unroll
            for (int f = 0; f < 4; ++f) {
                float p = __expf(pr[f][r] - mnew);
                pr[f][r] = p;
                sum += p;
            }
            sum += __shfl_xor(sum, 1, 64);
            sum += __shfl_xor(sum, 2, 64);
            sum += __shfl_xor(sum, 4, 64);
            sum += __shfl_xor(sum, 8, 64);
            lrun[r] = lrun[r] * fac + sum;
            #pragma unroll
            for (int df = 0; df < 4; ++df) oacc[df][r] *= fac;
        }

        // ---- P relayout through per-wave LDS ----
        #pragma unroll
        for (int f = 0; f < 4; ++f)
            #pragma unroll
            for (int r = 0; r < 4; ++r)
                Ps[w][g * 4 + r][16 * f + l16] = f2bf(pr[f][r]);
        asm volatile("s_waitcnt lgkmcnt(0)" ::: "memory");

        // ---- O += P @ V ----
        #pragma unroll
        for (int c = 0; c < 2; ++c) {
            short8 pa = *reinterpret_cast<const short8*>(&Ps[w][l16][32 * c + 8 * g]);
            #pragma unroll
            for (int df = 0; df < 4; ++df) {
                short8 bv = *reinterpret_cast<const short8*>(&Vts[16 * df + l16][32 * c + 8 * g]);
                oacc[df] = __builtin_amdgcn_mfma_f32_16x16x32_bf16(pa, bv, oacc[df], 0, 0, 0);
            }
        }
        __syncthreads();
    }

    float inv[4];
    #pragma unroll
    for (int r = 0; r < 4; ++r) inv[r] = 1.f / lrun[r];
    #pragma unroll
    for (int df = 0; df < 4; ++df) {
        #pragma unroll
        for (int r = 0; r < 4; ++r) {
            const int ig = q0 + w * 16 + g * 4 + r;
            if (ig < Nn)
                out[(size_t)(b * Nn + ig) * Cc + h * HD + 16 * df + l16] =
                    f2bf(oacc[df][r] * inv[r]);
        }
    }
}

extern "C" void kernel_launch(void* const* d_in, const int* in_sizes, int n_in,
                              void* d_out, int out_size, void* d_ws, size_t ws_size,
                              hipStream_t stream) {
    const float* x      = (const float*)d_in[0];
    const float* w_qkv  = (const float*)d_in[1];
    const float* b_qkv  = (const float*)d_in[2];
    const float* scale  = (const float*)d_in[3];
    const float* w_proj = (const float*)d_in[4];
    const float* b_proj = (const float*)d_in[5];
    float* out = (float*)d_out;

    const int B = 32, N = 577, C = 768, H = 12;
    const int M  = B * N;     // 18464
    const int C3 = 3 * C;     // 2304

    // workspace layout (~146 MB, all bf16)
    short* qkvb   = (short*)d_ws;                        // M x 3C bf16
    short* attn_o = qkvb + (size_t)M * C3;               // M x C bf16
    short* xb     = attn_o + (size_t)M * C;              // M x C bf16
    short* wqkvT  = xb + (size_t)M * C;                  // 3C x C bf16
    short* wprojT = wqkvT + (size_t)C3 * C;              // C x C bf16

    dim3 blk(256);
    const long n4 = (long)M * C / 4;
    convert_bf16<<<dim3((n4 + 255) / 256), blk, 0, stream>>>(x, xb, n4);
    transpose_bf16<<<dim3(C3 / 32, C / 32), blk, 0, stream>>>(w_qkv, wqkvT, C, C3);
    transpose_bf16<<<dim3(C / 32, C / 32), blk, 0, stream>>>(w_proj, wprojT, C, C);

    gemm_bf16<short><<<dim3(C3 / 128, (M + 127) / 128), blk, 0, stream>>>(
        xb, wqkvT, b_qkv, qkvb, M, C3, C);

    flash_attn<<<dim3(((N + 63) / 64) * H * B), blk, 0, stream>>>(qkvb, scale, attn_o);

    gemm_bf16<float><<<dim3(C / 128, (M + 127) / 128), blk, 0, stream>>>(
        attn_o, wprojT, b_proj, out, M, C, C);
}

// Round 6
// 307.558 us; speedup vs baseline: 30.7675x; 1.1352x over previous
//
#include <hip/hip_runtime.h>
#include <math.h>

#define HD 64
#define KVBLK 64
#define LP 72   // padded LDS row (bf16 elems) for V^T / P tiles

typedef __attribute__((ext_vector_type(8))) short short8;
typedef __attribute__((ext_vector_type(4))) short short4v;
typedef __attribute__((ext_vector_type(4))) float f32x4;

__device__ __forceinline__ short f2bf(float f) {
    union { float f; unsigned u; } in;
    in.f = f;
    unsigned r = (in.u + 0x7fff + ((in.u >> 16) & 1)) >> 16;  // RNE
    return (short)r;
}

// ---------------- fp32 -> bf16 convert (4 elems/thread) ----------------
__global__ __launch_bounds__(256) void convert_bf16(const float* __restrict__ in,
                                                    short* __restrict__ out, long n4) {
    long i = blockIdx.x * 256L + threadIdx.x;
    if (i >= n4) return;
    float4 v = reinterpret_cast<const float4*>(in)[i];
    short4v o;
    o[0] = f2bf(v.x); o[1] = f2bf(v.y); o[2] = f2bf(v.z); o[3] = f2bf(v.w);
    reinterpret_cast<short4v*>(out)[i] = o;
}

// ------------- transpose + convert: in [K][N] fp32 -> out [N][K] bf16 -------------
__global__ __launch_bounds__(256) void transpose_bf16(const float* __restrict__ in,
                                                      short* __restrict__ out, int K, int N) {
    __shared__ float tile[32][33];
    const int n0 = blockIdx.x * 32, k0 = blockIdx.y * 32;
    const int tx = threadIdx.x & 31, ty = threadIdx.x >> 5;
    #pragma unroll
    for (int i = ty; i < 32; i += 8)
        tile[i][tx] = in[(size_t)(k0 + i) * N + n0 + tx];
    __syncthreads();
    #pragma unroll
    for (int i = ty; i < 32; i += 8)
        out[(size_t)(n0 + i) * K + k0 + tx] = f2bf(tile[tx][i]);
}

// ---------------- bf16 MFMA GEMM (m97 structure), templated output ----------------
template <typename OutT>
__global__ __launch_bounds__(256) void gemm_bf16(const short* __restrict__ A,
                                                 const short* __restrict__ Bt,
                                                 const float* __restrict__ bias,
                                                 OutT* __restrict__ C,
                                                 int M, int N, int K) {
    __shared__ short As[128 * 64];
    __shared__ short Bs[128 * 64];
    const int tid = threadIdx.x;
    const int w = tid >> 6, lane = tid & 63;
    const int g = lane >> 4, l16 = lane & 15;
    const int m0 = blockIdx.y * 128, n0 = blockIdx.x * 128;
    const int wm = (w >> 1) * 64, wn = (w & 1) * 64;

    f32x4 acc[4][4] = {};

    const int lr = lane >> 3;
    const int lc = (lane & 7) * 8;

    for (int k0 = 0; k0 < K; k0 += 64) {
        #pragma unroll
        for (int t = 0; t < 4; ++t) {
            const int r = 32 * w + 8 * t + lr;
            long arow = m0 + r; if (arow > M - 1) arow = M - 1;
            const short* ga = A + arow * K + k0 + lc;
            const short* gb = Bt + (size_t)(n0 + r) * K + k0 + lc;
            __builtin_amdgcn_global_load_lds(
                (const __attribute__((address_space(1))) unsigned*)ga,
                (__attribute__((address_space(3))) unsigned*)&As[(32 * w + 8 * t) * 64],
                16, 0, 0);
            __builtin_amdgcn_global_load_lds(
                (const __attribute__((address_space(1))) unsigned*)gb,
                (__attribute__((address_space(3))) unsigned*)&Bs[(32 * w + 8 * t) * 64],
                16, 0, 0);
        }
        __syncthreads();
        #pragma unroll
        for (int ks = 0; ks < 2; ++ks) {
            short8 af[4], bfr[4];
            #pragma unroll
            for (int mi = 0; mi < 4; ++mi)
                af[mi] = *reinterpret_cast<const short8*>(
                    &As[(wm + mi * 16 + l16) * 64 + ks * 32 + g * 8]);
            #pragma unroll
            for (int ni = 0; ni < 4; ++ni)
                bfr[ni] = *reinterpret_cast<const short8*>(
                    &Bs[(wn + ni * 16 + l16) * 64 + ks * 32 + g * 8]);
            #pragma unroll
            for (int mi = 0; mi < 4; ++mi)
                #pragma unroll
                for (int ni = 0; ni < 4; ++ni)
                    acc[mi][ni] = __builtin_amdgcn_mfma_f32_16x16x32_bf16(
                        af[mi], bfr[ni], acc[mi][ni], 0, 0, 0);
        }
        __syncthreads();
    }

    float bv[4];
    #pragma unroll
    for (int ni = 0; ni < 4; ++ni) bv[ni] = bias[n0 + wn + ni * 16 + l16];
    #pragma unroll
    for (int mi = 0; mi < 4; ++mi) {
        #pragma unroll
        for (int r = 0; r < 4; ++r) {
            const int row = m0 + wm + mi * 16 + g * 4 + r;
            if (row < M) {
                #pragma unroll
                for (int ni = 0; ni < 4; ++ni) {
                    float val = acc[mi][ni][r] + bv[ni];
                    if constexpr (__is_same(OutT, float))
                        C[(size_t)row * N + n0 + wn + ni * 16 + l16] = val;
                    else
                        C[(size_t)row * N + n0 + wn + ni * 16 + l16] = f2bf(val);
                }
            }
        }
    }
}

// ---------------- flash attention: swapped-QK^T (S^T), in-lane softmax ----------------
// Block = (b, h, 64 q rows), 4 waves x 16 rows, XCD-swizzled grid.
// S^T = mfma(K_frag, Q_frag): lane holds 16 scores (keys 16f+4g+r) for q-row l16.
__global__ __launch_bounds__(256) void flash_attn(const short* __restrict__ qkvb,
                                                  const float* __restrict__ scale,
                                                  short* __restrict__ out) {
    constexpr int Nn = 577, Cc = 768, C3 = 2304, NQB = 10, NH = 12;
    const int bid = blockIdx.x;
    const int swz = (bid & 7) * 480 + (bid >> 3);   // T1: all 10 q-blocks of (b,h) on one XCD
    const int q0 = (swz % NQB) * 64;
    const int h  = (swz / NQB) % NH;
    const int b  = swz / (NQB * NH);

    const int tid  = threadIdx.x;
    const int w    = tid >> 6;
    const int lane = tid & 63;
    const int g    = lane >> 4;
    const int l16  = lane & 15;

    __shared__ alignas(16) short Ks[KVBLK * HD];   // linear, XOR-swizzled content
    __shared__ alignas(16) short Vts[HD][LP];      // V^T[dim][key]
    __shared__ alignas(16) short Ps[4][16][LP];    // per-wave P[qrow][key]
    __shared__ float facs[4][16];                  // per-wave stat broadcast

    const float sl2 = scale[h] * 1.44269504088896f;   // fold log2(e): exp2 domain
    const short* base = qkvb + (size_t)b * Nn * C3;
    const short* kglob = base + Cc + h * HD;
    const short* vglob = base + 2 * Cc + h * HD;

    // Q fragment (B operand now): per-lane 8 contiguous dims of q-row l16
    const int qrow = q0 + w * 16 + l16;
    const int qr = qrow < Nn ? qrow : Nn - 1;
    const short* qp = base + (size_t)qr * C3 + h * HD;
    short8 aq[2];
    aq[0] = *reinterpret_cast<const short8*>(qp + 8 * g);
    aq[1] = *reinterpret_cast<const short8*>(qp + 32 + 8 * g);

    f32x4 oacc[4] = {};           // O[qrow=g*4+r][n=16df+l16]
    float mrun = -INFINITY;       // stats for q-row l16 (uniform across g after reduce)
    float lrun = 0.f;

    const int tr = tid >> 2;
    const int tc = (tid & 3) * 16;
    const int kst_row = lane >> 3;
    const int kst_dblk = (lane & 7) ^ (lane >> 3);

    for (int kv0 = 0; kv0 < Nn; kv0 += KVBLK) {
        // ---- K tile via global_load_lds ----
        #pragma unroll
        for (int t = 0; t < 2; ++t) {
            const int i = 2 * w + t;
            int kr = kv0 + 8 * i + kst_row;
            if (kr > Nn - 1) kr = Nn - 1;
            const short* src = kglob + (size_t)kr * C3 + kst_dblk * 8;
            __builtin_amdgcn_global_load_lds(
                (const __attribute__((address_space(1))) unsigned*)src,
                (__attribute__((address_space(3))) unsigned*)&Ks[i * 512],
                16, 0, 0);
        }
        // ---- V tile: reg-staged transpose ----
        {
            int kr = kv0 + tr; if (kr > Nn - 1) kr = Nn - 1;
            const short* vsrc = vglob + (size_t)kr * C3 + tc;
            short8 v0 = *reinterpret_cast<const short8*>(vsrc);
            short8 v1 = *reinterpret_cast<const short8*>(vsrc + 8);
            #pragma unroll
            for (int i = 0; i < 8; ++i) {
                Vts[tc + i][tr]     = v0[i];
                Vts[tc + 8 + i][tr] = v1[i];
            }
        }
        __syncthreads();

        // ---- S^T = K @ Q^T : sacc[f] rows = keys 16f+4g+r, col = q-row l16 ----
        f32x4 sacc[4] = {};
        #pragma unroll
        for (int f = 0; f < 4; ++f) {
            #pragma unroll
            for (int c = 0; c < 2; ++c) {
                const int slot = (4 * c + g) ^ (l16 & 7);
                short8 ak = *reinterpret_cast<const short8*>(
                    &Ks[(16 * f + l16) * 64 + slot * 8]);
                sacc[f] = __builtin_amdgcn_mfma_f32_16x16x32_bf16(ak, aq[c], sacc[f], 0, 0, 0);
            }
        }

        // ---- mask + scale (exp2 domain); lane now owns 16 scores of q-row ig ----
        const int ig = q0 + w * 16 + l16;
        float s2[4][4];
        #pragma unroll
        for (int f = 0; f < 4; ++f) {
            #pragma unroll
            for (int r = 0; r < 4; ++r) {
                const int jg = kv0 + 16 * f + 4 * g + r;
                float s = sacc[f][r] * sl2;
                if (jg >= Nn || (jg == ig && ig >= 1)) s = -INFINITY;
                s2[f][r] = s;
            }
        }

        // ---- in-lane max (15 ops) + 2 shuffles across g ----
        float mx = s2[0][0];
        #pragma unroll
        for (int f = 0; f < 4; ++f)
            #pragma unroll
            for (int r = 0; r < 4; ++r)
                if (f + r) mx = fmaxf(mx, s2[f][r]);
        mx = fmaxf(mx, __shfl_xor(mx, 16, 64));
        mx = fmaxf(mx, __shfl_xor(mx, 32, 64));
        const float mnew = fmaxf(mrun, mx);
        const float fac = __builtin_amdgcn_exp2f(mrun - mnew);
        mrun = mnew;

        float sum = 0.f;
        #pragma unroll
        for (int f = 0; f < 4; ++f)
            #pragma unroll
            for (int r = 0; r < 4; ++r) {
                float p = __builtin_amdgcn_exp2f(s2[f][r] - mnew);
                s2[f][r] = p;
                sum += p;
            }
        sum += __shfl_xor(sum, 16, 64);
        sum += __shfl_xor(sum, 32, 64);
        lrun = lrun * fac + sum;

        // ---- broadcast fac (stats live at qrow=l16; oacc rows are qrow=4g+r) ----
        if (lane < 16) facs[w][lane] = fac;
        asm volatile("s_waitcnt lgkmcnt(0)" ::: "memory");
        #pragma unroll
        for (int r = 0; r < 4; ++r) {
            const float fr = facs[w][4 * g + r];
            #pragma unroll
            for (int df = 0; df < 4; ++df) oacc[df][r] *= fr;
        }

        // ---- packed P store: lane's keys 16f+4g..+3 are consecutive -> b64 ----
        #pragma unroll
        for (int f = 0; f < 4; ++f) {
            short4v pk;
            #pragma unroll
            for (int r = 0; r < 4; ++r) pk[r] = f2bf(s2[f][r]);
            *reinterpret_cast<short4v*>(&Ps[w][l16][16 * f + 4 * g]) = pk;
        }
        asm volatile("s_waitcnt lgkmcnt(0)" ::: "memory");

        // ---- O += P @ V ----
        #pragma unroll
        for (int c = 0; c < 2; ++c) {
            short8 pa = *reinterpret_cast<const short8*>(&Ps[w][l16][32 * c + 8 * g]);
            #pragma unroll
            for (int df = 0; df < 4; ++df) {
                short8 bv = *reinterpret_cast<const short8*>(&Vts[16 * df + l16][32 * c + 8 * g]);
                oacc[df] = __builtin_amdgcn_mfma_f32_16x16x32_bf16(pa, bv, oacc[df], 0, 0, 0);
            }
        }
        __syncthreads();
    }

    // ---- epilogue: broadcast lrun, normalize, store ----
    if (lane < 16) facs[w][lane] = lrun;
    asm volatile("s_waitcnt lgkmcnt(0)" ::: "memory");
    #pragma unroll
    for (int r = 0; r < 4; ++r) {
        const int og = q0 + w * 16 + g * 4 + r;
        if (og < Nn) {
            const float inv = 1.f / facs[w][4 * g + r];
            #pragma unroll
            for (int df = 0; df < 4; ++df)
                out[(size_t)(b * Nn + og) * Cc + h * HD + 16 * df + l16] =
                    f2bf(oacc[df][r] * inv);
        }
    }
}

extern "C" void kernel_launch(void* const* d_in, const int* in_sizes, int n_in,
                              void* d_out, int out_size, void* d_ws, size_t ws_size,
                              hipStream_t stream) {
    const float* x      = (const float*)d_in[0];
    const float* w_qkv  = (const float*)d_in[1];
    const float* b_qkv  = (const float*)d_in[2];
    const float* scale  = (const float*)d_in[3];
    const float* w_proj = (const float*)d_in[4];
    const float* b_proj = (const float*)d_in[5];
    float* out = (float*)d_out;

    const int B = 32, N = 577, C = 768, H = 12;
    const int M  = B * N;
    const int C3 = 3 * C;

    short* qkvb   = (short*)d_ws;
    short* attn_o = qkvb + (size_t)M * C3;
    short* xb     = attn_o + (size_t)M * C;
    short* wqkvT  = xb + (size_t)M * C;
    short* wprojT = wqkvT + (size_t)C3 * C;

    dim3 blk(256);
    const long n4 = (long)M * C / 4;
    convert_bf16<<<dim3((n4 + 255) / 256), blk, 0, stream>>>(x, xb, n4);
    transpose_bf16<<<dim3(C3 / 32, C / 32), blk, 0, stream>>>(w_qkv, wqkvT, C, C3);
    transpose_bf16<<<dim3(C / 32, C / 32), blk, 0, stream>>>(w_proj, wprojT, C, C);

    gemm_bf16<short><<<dim3(C3 / 128, (M + 127) / 128), blk, 0, stream>>>(
        xb, wqkvT, b_qkv, qkvb, M, C3, C);

    flash_attn<<<dim3(((N + 63) / 64) * H * B), blk, 0, stream>>>(qkvb, scale, attn_o);

    gemm_bf16<float><<<dim3(C / 128, (M + 127) / 128), blk, 0, stream>>>(
        attn_o, wprojT, b_proj, out, M, C, C);
}